// Round 6
// baseline (65.208 us; speedup 1.0000x reference)
//
#include <hip/hip_runtime.h>
#include <cmath>

constexpr int NN    = 1536;      // nodes
constexpr int FF    = 512;       // in features
constexpr int HH    = 64;        // hidden
constexpr int RPB   = 16;        // rows per block (MFMA M)
constexpr int NB    = NN / RPB;  // 96 blocks (<= 256 CUs, coop-resident)
constexpr int NT    = 1024;      // 16 waves
constexpr int WAVES = NT / 64;
constexpr int KST   = NN / 32;   // 48 k-steps of 32
constexpr int KST1  = FF / 32;   // 16 k-steps for x@W1

using f32x4  = __attribute__((ext_vector_type(4))) float;
using bf16x8 = __attribute__((ext_vector_type(8))) short;
typedef unsigned short u16;

__device__ __forceinline__ u16 f2bf(float f) {  // RNE fp32 -> bf16
  unsigned u = __builtin_bit_cast(unsigned, f);
  return (u16)((u + 0x7fffu + ((u >> 16) & 1u)) >> 16);
}

struct Params {
  const float *x, *adj, *W1, *b1, *W2, *b2, *W3, *b3;
  u16 *t1T, *B2T, *B3T;
  float* out;
  unsigned* bar;
};

// Grid barrier: RELEASE arrive (buffer_wbl2 -> T visible at IC), RELAXED poll
// (no per-poll L2 invalidate -- round 3's mistake), ONE acquire RMW at exit
// (single buffer_inv). Counter is monotonic across the 3 barriers; memset to
// 0 at the start of every kernel_launch call.
__device__ __forceinline__ void gbar(unsigned* c, unsigned target) {
  __syncthreads();  // all waves' global stores drained (vmcnt 0) before arrive
  if (threadIdx.x == 0) {
    __hip_atomic_fetch_add(c, 1u, __ATOMIC_RELEASE, __HIP_MEMORY_SCOPE_AGENT);
    while (__hip_atomic_load(c, __ATOMIC_RELAXED, __HIP_MEMORY_SCOPE_AGENT) <
           target)
      __builtin_amdgcn_s_sleep(4);
    __hip_atomic_fetch_add(c, 0u, __ATOMIC_ACQUIRE, __HIP_MEMORY_SCOPE_AGENT);
  }
  __syncthreads();
}

// Tile conventions (A/B share the k-map => dot product invariant to HW k-order):
//  A-tile (16 r x 32 k): hw idx = kstep*512 + ((k&31)>>3)*128 + r*8 + (k&7)
//  B-tile (32 k x 16 c): idx = (kstep*4 + c/16)*512 + ((k&31)>>3)*128 + (c&15)*8 + (k&7)
//  C/D (m89-verified): col = lane&15, row = (lane>>4)*4 + reg

__global__ __launch_bounds__(NT, 4) void gcn_all(Params p) {
  __shared__ u16 adjL[KST * 512];                               // 48 KB
  __shared__ __attribute__((aligned(16))) char uni[96 * 1024];  // 96 KB union
  __shared__ float xloc[RPB][HH];                               // 4 KB
  __shared__ float anext[RPB][HH];                              // 4 KB
  __shared__ float degs[RPB];

  u16*   Al   = (u16*)uni;                  // 16 KB   (phase 0)
  u16*   Bl   = (u16*)(uni + 16 * 1024);    // 64 KB   (phase 0)
  float* red0 = (float*)(uni + 80 * 1024);  // 16 KB   (phase 0) [4][4][16][16]
  float* Wl   = (float*)uni;                // 32 KB   (layers)
  float* red  = (float*)(uni + 32 * 1024);  // 64 KB   (layers) [16][4][16][16]

  const int tid = threadIdx.x, lane = tid & 63, wave = tid >> 6;
  const int i0 = blockIdx.x * RPB;

  // ---- pack x rows -> Al (wave = row, lane covers 8 k) ----
  {
    int j0 = lane * 8;
    const float* src = p.x + (size_t)(i0 + wave) * FF + j0;
    bf16x8 v;
#pragma unroll
    for (int jj = 0; jj < 8; ++jj) v[jj] = (short)f2bf(src[jj]);
    *(bf16x8*)&Al[(j0 >> 5) * 512 + ((j0 & 31) >> 3) * 128 + wave * 8] = v;
  }
  // ---- pack W1 -> Bl (thread: one k-row, 32 cols, float4 reads) ----
  {
    int k = tid >> 1, c0 = (tid & 1) * 32;
    const float4* src = (const float4*)(p.W1 + (size_t)k * HH + c0);
    int base = (k >> 5) * 2048 + ((k & 31) >> 3) * 128 + (k & 7);
#pragma unroll
    for (int g = 0; g < 8; ++g) {
      float4 f = src[g];
      int c = c0 + g * 4;
      int off = base + (c >> 4) * 512 + (c & 15) * 8;
      Bl[off]      = f2bf(f.x);
      Bl[off + 8]  = f2bf(f.y);
      Bl[off + 16] = f2bf(f.z);
      Bl[off + 24] = f2bf(f.w);
    }
  }
  // ---- pack adj slab -> adjL (LDS, persists all 3 layers) + deg ----
  {
    int j0 = lane * 24;
    const float* src = p.adj + (size_t)(i0 + wave) * NN + j0;
    float ds = 0.f;
#pragma unroll
    for (int g = 0; g < 3; ++g) {
      bf16x8 v;
#pragma unroll
      for (int jj = 0; jj < 8; ++jj) {
        float f = src[g * 8 + jj];
        ds += f;
        v[jj] = (short)f2bf(f);
      }
      int k = j0 + g * 8;
      *(bf16x8*)&adjL[(k >> 5) * 512 + ((k & 31) >> 3) * 128 + wave * 8] = v;
    }
#pragma unroll
    for (int off = 32; off; off >>= 1) ds += __shfl_xor(ds, off, 64);
    if (lane == 0) degs[wave] = ds;
  }
  __syncthreads();

  // ---- phase 0: t1 = x @ W1 (own 16 rows) ----
  {
    int ks = wave >> 2, cg = wave & 3;
    f32x4 acc = {0.f, 0.f, 0.f, 0.f};
#pragma unroll
    for (int s = 0; s < 4; ++s) {
      int t = ks * 4 + s;
      bf16x8 a = *(const bf16x8*)&Al[t * 512 + lane * 8];
      bf16x8 b = *(const bf16x8*)&Bl[(t * 4 + cg) * 512 + lane * 8];
      acc = __builtin_amdgcn_mfma_f32_16x16x32_bf16(a, b, acc, 0, 0, 0);
    }
#pragma unroll
    for (int q = 0; q < 4; ++q)
      red0[((ks * 4 + cg) * 16 + ((lane >> 4) * 4 + q)) * 16 + (lane & 15)] =
          acc[q];
  }
  __syncthreads();
  {  // combine 4 k-segments, store t1 -> t1T (global bf16 B-tiles)
    int r = wave, c = lane;
    float v = 0.f;
#pragma unroll
    for (int ks2 = 0; ks2 < 4; ++ks2)
      v += red0[((ks2 * 4 + (c >> 4)) * 16 + r) * 16 + (c & 15)];
    int k = i0 + r;
    p.t1T[((k >> 5) * 4 + (c >> 4)) * 512 + ((k & 31) >> 3) * 128 +
          (c & 15) * 8 + (k & 7)] = f2bf(v);
  }
  __syncthreads();  // red0/Al/Bl dead; uni becomes Wl+red
  // ---- stage W2 -> Wl (before barrier: hides IC latency) ----
  {
    const float4* src = (const float4*)p.W2;
    float4* dst = (float4*)Wl;
#pragma unroll
    for (int s = 0; s < 2; ++s) dst[tid + s * NT] = src[tid + s * NT];
  }
  gbar(p.bar, NB);

  // ---- layers 0..2 ----
#pragma unroll 1
  for (int l = 0; l < 3; ++l) {
    const u16* TT    = l == 0 ? p.t1T : (l == 1 ? p.B2T : p.B3T);
    const float* bia = l == 0 ? p.b1 : (l == 1 ? p.b2 : p.b3);
    u16* Bout        = l == 0 ? p.B2T : p.B3T;

    // K-loop: a-frags from LDS adjL, b-frags from global TT (IC/L2)
    bf16x8 a[3], b[3][4];
#pragma unroll
    for (int s = 0; s < 3; ++s) {
      int kst = wave * 3 + s;
      a[s] = *(const bf16x8*)&adjL[kst * 512 + lane * 8];
#pragma unroll
      for (int cg = 0; cg < 4; ++cg)
        b[s][cg] =
            *(const bf16x8*)(TT + (size_t)(kst * 4 + cg) * 512 + lane * 8);
    }
    f32x4 acc[4] = {{0, 0, 0, 0}, {0, 0, 0, 0}, {0, 0, 0, 0}, {0, 0, 0, 0}};
#pragma unroll
    for (int s = 0; s < 3; ++s)
#pragma unroll
      for (int cg = 0; cg < 4; ++cg)
        acc[cg] =
            __builtin_amdgcn_mfma_f32_16x16x32_bf16(a[s], b[s][cg], acc[cg], 0, 0, 0);
#pragma unroll
    for (int cg = 0; cg < 4; ++cg)
#pragma unroll
      for (int q = 0; q < 4; ++q)
        red[((wave * 4 + cg) * 16 + ((lane >> 4) * 4 + q)) * 16 + (lane & 15)] =
            acc[cg][q];
    __syncthreads();

    {  // combine 16 k-segments + bias + deg term + activation
      int r = wave, c = lane;
      float v = bia[c];
#pragma unroll
      for (int w = 0; w < WAVES; ++w)
        v += red[((w * 4 + (c >> 4)) * 16 + r) * 16 + (c & 15)];
      if (l >= 1) v += anext[r][c] * degs[r];
      if (l == 0) v = fmaxf(v, 0.f);
      if (l == 1) v = v > 0.f ? v : expm1f(v);
      xloc[r][c] = v;
    }
    __syncthreads();

    if (l < 2) {
      // anext (LDS) = x @ Wn[:64];  B_next (global bf16 tiles) = x @ Wn[64:]
#pragma unroll
      for (int t = 0; t < 2; ++t) {
        int idx = tid + t * NT;
        int r = idx >> 7, cc = idx & 127, half = cc >> 6, col = cc & 63;
        float s = 0.f;
#pragma unroll
        for (int k = 0; k < HH; ++k)
          s = fmaf(xloc[r][k], Wl[(half * HH + k) * HH + col], s);
        if (half == 0) {
          anext[r][col] = s;
        } else {
          int kk = i0 + r;
          Bout[((kk >> 5) * 4 + (col >> 4)) * 512 + ((kk & 31) >> 3) * 128 +
               (col & 15) * 8 + (kk & 7)] = f2bf(s);
        }
      }
      __syncthreads();  // Wl fully consumed
      if (l == 0) {     // stage W3 before the barrier
        const float4* src = (const float4*)p.W3;
        float4* dst = (float4*)Wl;
#pragma unroll
        for (int s2 = 0; s2 < 2; ++s2) dst[tid + s2 * NT] = src[tid + s2 * NT];
      }
      gbar(p.bar, (unsigned)((2 + l) * NB));
    } else {
      // log_softmax: wave = row
      float v = xloc[wave][lane];
      float m = v;
#pragma unroll
      for (int off = 32; off; off >>= 1) m = fmaxf(m, __shfl_xor(m, off, 64));
      float e = expf(v - m);
      float ssum = e;
#pragma unroll
      for (int off = 32; off; off >>= 1) ssum += __shfl_xor(ssum, off, 64);
      p.out[(size_t)(i0 + wave) * HH + lane] = v - m - logf(ssum);
    }
  }
}

extern "C" void kernel_launch(void* const* d_in, const int* in_sizes, int n_in,
                              void* d_out, int out_size, void* d_ws,
                              size_t ws_size, hipStream_t stream) {
  Params p;
  p.x   = (const float*)d_in[0];
  p.adj = (const float*)d_in[2];  // adj1; d_in[1]/d_in[3] are dead inputs
  p.W1  = (const float*)d_in[4];
  p.b1  = (const float*)d_in[5];
  p.W2  = (const float*)d_in[6];
  p.b2  = (const float*)d_in[7];
  p.W3  = (const float*)d_in[8];
  p.b3  = (const float*)d_in[9];
  p.out = (float*)d_out;

  char* ws = (char*)d_ws;
  p.t1T = (u16*)ws;                       // 196,608 B each
  p.B2T = (u16*)(ws + 196608);
  p.B3T = (u16*)(ws + 393216);
  p.bar = (unsigned*)(ws + 589824);       // one cache line

  // barrier counter must be 0 at the start of every call
  hipMemsetAsync((void*)p.bar, 0, 128, stream);

  void* args[] = {&p};
  hipLaunchCooperativeKernel((const void*)gcn_all, dim3(NB), dim3(NT), args, 0,
                             stream);
}

// Round 7
// 61.937 us; speedup vs baseline: 1.0528x; 1.0528x over previous
//
#include <hip/hip_runtime.h>
#include <cmath>

constexpr int NN    = 1536;      // nodes
constexpr int FF    = 512;       // in features
constexpr int HH    = 64;        // hidden
constexpr int RPB   = 16;        // rows per block (MFMA M)
constexpr int NB    = NN / RPB;  // 96 blocks (coop-resident)
constexpr int NT    = 1024;      // 16 waves
constexpr int WAVES = NT / 64;
constexpr int KST   = NN / 32;   // 48 k-steps of 32

// padded red strides (floats): row 17, cg 272, wave-seg 1092  -> all <=2-way banks
constexpr int RED_R = 17, RED_CG = 272, RED_W = 1092;

using f32x4  = __attribute__((ext_vector_type(4))) float;
using bf16x8 = __attribute__((ext_vector_type(8))) short;
typedef unsigned short u16;

__device__ __forceinline__ u16 f2bf(float f) {  // RNE fp32 -> bf16
  unsigned u = __builtin_bit_cast(unsigned, f);
  return (u16)((u + 0x7fffu + ((u >> 16) & 1u)) >> 16);
}

struct Params {
  const float *x, *adj, *W1, *b1, *W2, *b2, *W3, *b3;
  u16 *t1T, *B2T, *B3T;
  float* out;
  unsigned* bar;
};

// release arrive / relaxed poll / one acquire at exit (counter memset per call)
__device__ __forceinline__ void gbar(unsigned* c, unsigned target) {
  __syncthreads();
  if (threadIdx.x == 0) {
    __hip_atomic_fetch_add(c, 1u, __ATOMIC_RELEASE, __HIP_MEMORY_SCOPE_AGENT);
    while (__hip_atomic_load(c, __ATOMIC_RELAXED, __HIP_MEMORY_SCOPE_AGENT) <
           target)
      __builtin_amdgcn_s_sleep(1);
    __hip_atomic_fetch_add(c, 0u, __ATOMIC_ACQUIRE, __HIP_MEMORY_SCOPE_AGENT);
  }
  __syncthreads();
}

// Tile conventions (A/B share the k-map => dot product invariant to HW k-order):
//  A-tile (16 r x 32 k): hw idx = kstep*512 + ((k&31)>>3)*128 + r*8 + (k&7)
//  B-tile (32 k x 16 c): idx = (kstep*4 + c/16)*512 + ((k&31)>>3)*128 + (c&15)*8 + (k&7)
//  C/D: col = lane&15, row = (lane>>4)*4 + reg

__global__ __launch_bounds__(NT, 4) void gcn_all(Params p) {
  __shared__ u16 adjL[KST * 512];                                // 48 KB
  __shared__ __attribute__((aligned(16))) char uni[103168];      // ~100.8 KB
  __shared__ float xloc[RPB][HH];                                // 4 KB
  __shared__ float anext[RPB][HH];                               // 4 KB
  __shared__ float degs[RPB];

  // phase-0 overlay
  u16*   Al   = (u16*)uni;                  // 16 KB
  u16*   Bl   = (u16*)(uni + 16384);        // 64 KB
  float* red0 = (float*)(uni + 81920);      // 16 KB  [4][4][16][16]
  // layer overlay
  float* WlT  = (float*)uni;                // 33,280 B: [2][64][65] transposed W
  float* red  = (float*)(uni + 33280);      // 69,888 B: padded [16]x[4]x[16]x[16]

  const int tid = threadIdx.x, lane = tid & 63, wave = tid >> 6;
  const int i0 = blockIdx.x * RPB;

  // ---- pack x rows -> Al (wave = row, lane covers 8 k) ----
  {
    int j0 = lane * 8;
    const float* src = p.x + (size_t)(i0 + wave) * FF + j0;
    bf16x8 v;
#pragma unroll
    for (int jj = 0; jj < 8; ++jj) v[jj] = (short)f2bf(src[jj]);
    *(bf16x8*)&Al[(j0 >> 5) * 512 + ((j0 & 31) >> 3) * 128 + wave * 8] = v;
  }
  // ---- pack W1 -> Bl (coalesced col reads, contiguous bf16x8 writes) ----
  {
    int c = tid & 63, z = tid >> 6;
#pragma unroll
    for (int rep = 0; rep < 4; ++rep) {
      int k0 = (z + 16 * rep) * 8;
      bf16x8 v;
#pragma unroll
      for (int i = 0; i < 8; ++i) v[i] = (short)f2bf(p.W1[(size_t)(k0 + i) * HH + c]);
      *(bf16x8*)&Bl[(k0 >> 5) * 2048 + (c >> 4) * 512 + ((k0 & 31) >> 3) * 128 +
                    (c & 15) * 8] = v;
    }
  }
  // ---- pack adj slab -> adjL (persists all 3 layers) + deg ----
  {
    int j0 = lane * 24;
    const float* src = p.adj + (size_t)(i0 + wave) * NN + j0;
    float ds = 0.f;
#pragma unroll
    for (int g = 0; g < 3; ++g) {
      bf16x8 v;
#pragma unroll
      for (int jj = 0; jj < 8; ++jj) {
        float f = src[g * 8 + jj];
        ds += f;
        v[jj] = (short)f2bf(f);
      }
      int k = j0 + g * 8;
      *(bf16x8*)&adjL[(k >> 5) * 512 + ((k & 31) >> 3) * 128 + wave * 8] = v;
    }
#pragma unroll
    for (int off = 32; off; off >>= 1) ds += __shfl_xor(ds, off, 64);
    if (lane == 0) degs[wave] = ds;
  }
  __syncthreads();

  // ---- phase 0: t1 = x @ W1 ----
  {
    int ks = wave >> 2, cg = wave & 3;
    f32x4 acc = {0.f, 0.f, 0.f, 0.f};
#pragma unroll
    for (int s = 0; s < 4; ++s) {
      int t = ks * 4 + s;
      bf16x8 a = *(const bf16x8*)&Al[t * 512 + lane * 8];
      bf16x8 b = *(const bf16x8*)&Bl[(t * 4 + cg) * 512 + lane * 8];
      acc = __builtin_amdgcn_mfma_f32_16x16x32_bf16(a, b, acc, 0, 0, 0);
    }
#pragma unroll
    for (int q = 0; q < 4; ++q)
      red0[((ks * 4 + cg) * 16 + ((lane >> 4) * 4 + q)) * 16 + (lane & 15)] = acc[q];
  }
  __syncthreads();
  {  // combine 4 k-segments, store t1 -> t1T (global bf16 B-tiles)
    int r = wave, c = lane;
    float v = 0.f;
#pragma unroll
    for (int ks2 = 0; ks2 < 4; ++ks2)
      v += red0[((ks2 * 4 + (c >> 4)) * 16 + r) * 16 + (c & 15)];
    int k = i0 + r;
    p.t1T[((k >> 5) * 4 + (c >> 4)) * 512 + ((k & 31) >> 3) * 128 +
          (c & 15) * 8 + (k & 7)] = f2bf(v);
  }
  __syncthreads();  // phase-0 overlay dead

  // ---- stage W2 -> WlT transposed [half][col][65] ----
  {
    int c = tid & 63, z = tid >> 6;  // z: half = z>>3, kg = z&7
    int half = z >> 3, kg = z & 7;
#pragma unroll
    for (int i = 0; i < 8; ++i)
      WlT[half * 4160 + c * 65 + kg * 8 + i] =
          p.W2[(size_t)(half * HH + kg * 8 + i) * HH + c];
  }
  gbar(p.bar, NB);

  // ---- layers 0..2 ----
#pragma unroll 1
  for (int l = 0; l < 3; ++l) {
    const u16* TT    = l == 0 ? p.t1T : (l == 1 ? p.B2T : p.B3T);
    const float* bia = l == 0 ? p.b1 : (l == 1 ? p.b2 : p.b3);
    u16* Bout        = l == 0 ? p.B2T : p.B3T;

    // K-loop: issue ALL 12 IC loads + 3 LDS reads, pin them above the MFMAs
    const int kbase = wave * 3;
    bf16x8 a[3], b[3][4];
#pragma unroll
    for (int s = 0; s < 3; ++s) {
      const u16* tb = TT + (size_t)((kbase + s) * 4) * 512 + lane * 8;
#pragma unroll
      for (int cg = 0; cg < 4; ++cg) b[s][cg] = *(const bf16x8*)(tb + cg * 512);
    }
#pragma unroll
    for (int s = 0; s < 3; ++s)
      a[s] = *(const bf16x8*)&adjL[(kbase + s) * 512 + lane * 8];
    __builtin_amdgcn_sched_barrier(0);
    f32x4 acc[4] = {{0, 0, 0, 0}, {0, 0, 0, 0}, {0, 0, 0, 0}, {0, 0, 0, 0}};
#pragma unroll
    for (int s = 0; s < 3; ++s)
#pragma unroll
      for (int cg = 0; cg < 4; ++cg)
        acc[cg] = __builtin_amdgcn_mfma_f32_16x16x32_bf16(a[s], b[s][cg], acc[cg], 0, 0, 0);
#pragma unroll
    for (int cg = 0; cg < 4; ++cg)
#pragma unroll
      for (int q = 0; q < 4; ++q)
        red[wave * RED_W + cg * RED_CG + ((lane >> 4) * 4 + q) * RED_R +
            (lane & 15)] = acc[cg][q];
    __syncthreads();

    {  // combine 16 k-segments + bias + deg term + activation
      int r = wave, c = lane;
      float v = bia[c];
#pragma unroll
      for (int w = 0; w < WAVES; ++w)
        v += red[w * RED_W + (c >> 4) * RED_CG + r * RED_R + (c & 15)];
      if (l >= 1) v += anext[r][c] * degs[r];
      if (l == 0) v = fmaxf(v, 0.f);
      if (l == 1) v = v > 0.f ? v : expm1f(v);
      xloc[r][c] = v;
    }
    __syncthreads();

    if (l < 2) {
      // epilogue: anext = x@Wn[:64], Bout = x@Wn[64:] (bf16x8 stores along k)
      const int rg = tid >> 9, cc = (tid >> 3) & 63, kq = tid & 7;
#pragma unroll
      for (int half = 0; half < 2; ++half) {
        float pj[8];
#pragma unroll
        for (int j = 0; j < 8; ++j) {
          float s = 0.f;
#pragma unroll
          for (int i = 0; i < 8; ++i)
            s = fmaf(xloc[rg * 8 + j][kq * 8 + i],
                     WlT[half * 4160 + cc * 65 + kq * 8 + i], s);
          pj[j] = s;
        }
#pragma unroll
        for (int off = 1; off < 8; off <<= 1)
#pragma unroll
          for (int j = 0; j < 8; ++j) pj[j] += __shfl_xor(pj[j], off, 64);
        if (kq == 0) {
          if (half == 0) {
#pragma unroll
            for (int j = 0; j < 8; ++j) anext[rg * 8 + j][cc] = pj[j];
          } else {
            bf16x8 v;
#pragma unroll
            for (int j = 0; j < 8; ++j) v[j] = (short)f2bf(pj[j]);
            int kk0 = i0 + rg * 8;  // 8-aligned
            *(bf16x8*)&Bout[(size_t)((kk0 >> 5) * 4 + (cc >> 4)) * 512 +
                            ((kk0 & 31) >> 3) * 128 + (cc & 15) * 8] = v;
          }
        }
      }
      __syncthreads();  // WlT consumed
      if (l == 0) {     // stage W3 transposed before the barrier
        int c = tid & 63, z = tid >> 6;
        int half = z >> 3, kg = z & 7;
#pragma unroll
        for (int i = 0; i < 8; ++i)
          WlT[half * 4160 + c * 65 + kg * 8 + i] =
              p.W3[(size_t)(half * HH + kg * 8 + i) * HH + c];
      }
      gbar(p.bar, (unsigned)((2 + l) * NB));
    } else {
      // log_softmax: wave = row
      float v = xloc[wave][lane];
      float m = v;
#pragma unroll
      for (int off = 32; off; off >>= 1) m = fmaxf(m, __shfl_xor(m, off, 64));
      float e = expf(v - m);
      float ssum = e;
#pragma unroll
      for (int off = 32; off; off >>= 1) ssum += __shfl_xor(ssum, off, 64);
      p.out[(size_t)(i0 + wave) * HH + lane] = v - m - logf(ssum);
    }
  }
}

extern "C" void kernel_launch(void* const* d_in, const int* in_sizes, int n_in,
                              void* d_out, int out_size, void* d_ws,
                              size_t ws_size, hipStream_t stream) {
  Params p;
  p.x   = (const float*)d_in[0];
  p.adj = (const float*)d_in[2];  // adj1; d_in[1]/d_in[3] are dead inputs
  p.W1  = (const float*)d_in[4];
  p.b1  = (const float*)d_in[5];
  p.W2  = (const float*)d_in[6];
  p.b2  = (const float*)d_in[7];
  p.W3  = (const float*)d_in[8];
  p.b3  = (const float*)d_in[9];
  p.out = (float*)d_out;

  char* ws = (char*)d_ws;
  p.t1T = (u16*)ws;                  // 196,608 B each
  p.B2T = (u16*)(ws + 196608);
  p.B3T = (u16*)(ws + 393216);
  p.bar = (unsigned*)(ws + 589824);  // one cache line

  hipMemsetAsync((void*)p.bar, 0, 128, stream);

  void* args[] = {&p};
  hipLaunchCooperativeKernel((const void*)gcn_all, dim3(NB), dim3(NT), args, 0,
                             stream);
}

// Round 9
// 54.676 us; speedup vs baseline: 1.1926x; 1.1328x over previous
//
#include <hip/hip_runtime.h>
#include <cmath>

constexpr int NN    = 1536;      // nodes
constexpr int FF    = 512;       // in features
constexpr int HH    = 64;        // hidden
constexpr int RPB   = 16;        // rows per block
constexpr int NB    = NN / RPB;  // 96 blocks, 1/CU (LDS-limited)
constexpr int NT    = 1024;      // 16 waves
constexpr int KST   = NN / 32;   // 48 k-steps

// LDS byte offsets (manual union) -- sizes in BYTES (r8 bug: WnB was sized in u16)
constexpr int O_TTL  = 0;        //  98304: layer T-half staging [16 waves][6KB]
constexpr int O_ADJ  = 0;        //  49152: pre: adj A-tiles (48 tiles x 1KB)
constexpr int O_XR   = 49152;    //  32768: pre: x rows f32 [16][512]
constexpr int O_RED8 = 98304;    //  34816: [8][4][16][17] f32
constexpr int O_WNB  = 133120;   //  16384: [2 ks][8 cg][512] u16  (epilogue W)
constexpr int O_XA   = 149504;   //   2048: x as bf16 A-tiles [2][512] u16
constexpr int O_XLOC = 151552;   //   4160: [16][65] f32
constexpr int O_ANX  = 155712;   //   4160: [16][65] f32
constexpr int O_DEG  = 159872;   //     64
constexpr int LDS_SZ = 159936;   // 156.2 KB -> 1 block/CU

using f32x4  = __attribute__((ext_vector_type(4))) float;
using bf16x8 = __attribute__((ext_vector_type(8))) short;
using u16x4  = __attribute__((ext_vector_type(4))) unsigned short;
typedef unsigned short u16;

__device__ __forceinline__ u16 f2bf(float f) {  // RNE fp32 -> bf16
  unsigned u = __builtin_bit_cast(unsigned, f);
  return (u16)((u + 0x7fffu + ((u >> 16) & 1u)) >> 16);
}

// B-tile buffer index for a [1536 k x 64 c] matrix, column-half contiguous:
// half (c>>5) spans a contiguous 96KB; tile = k-step*2 + ((c>>4)&1).
__device__ __forceinline__ size_t bidx(int k, int c) {
  return (size_t)((c >> 5) * (KST * 2) + (k >> 5) * 2 + ((c >> 4) & 1)) * 512 +
         ((k & 31) >> 3) * 128 + (c & 15) * 8 + (k & 7);
}

__device__ __forceinline__ void gl_lds16(const void* g, void* l) {
  __builtin_amdgcn_global_load_lds(
      (const __attribute__((address_space(1))) unsigned*)g,
      (__attribute__((address_space(3))) unsigned*)l, 16, 0, 0);
}

struct Params {
  const float *x, *adj, *W1, *b1, *W2, *b2, *W3, *b3;
  u16 *t1T, *B2T, *B3T;
  float* out;
  unsigned* bar;
};

// release arrive / relaxed poll / one acquire at exit
__device__ __forceinline__ void gbar(unsigned* c, unsigned target) {
  __syncthreads();
  if (threadIdx.x == 0) {
    __hip_atomic_fetch_add(c, 1u, __ATOMIC_RELEASE, __HIP_MEMORY_SCOPE_AGENT);
    while (__hip_atomic_load(c, __ATOMIC_RELAXED, __HIP_MEMORY_SCOPE_AGENT) <
           target)
      __builtin_amdgcn_s_sleep(1);
    __hip_atomic_fetch_add(c, 0u, __ATOMIC_ACQUIRE, __HIP_MEMORY_SCOPE_AGENT);
  }
  __syncthreads();
}

__device__ __forceinline__ void pack_wnb(u16* WnB, const float* Wsrc, int tid) {
  // Bmat[k][j'], k 0..63, j' 0..127; j'<64 -> Wn[k][j'], else Wn[64+k][j'-64]
  int jp = tid & 127, kb = (tid >> 7) * 8;
  int srow0 = (jp >> 6) * 64, col = jp & 63;
#pragma unroll
  for (int i = 0; i < 8; ++i) {
    int k = kb + i;
    WnB[((k >> 5) * 8 + (jp >> 4)) * 512 + ((k & 31) >> 3) * 128 +
        (jp & 15) * 8 + (k & 7)] = f2bf(Wsrc[(size_t)(srow0 + k) * HH + col]);
  }
}

__global__ __launch_bounds__(NT, 4) void gcn_all(Params p) {
  __shared__ __attribute__((aligned(16))) char LB[LDS_SZ];
  u16*   adjL = (u16*)(LB + O_ADJ);
  float* xr   = (float*)(LB + O_XR);
  float* red8 = (float*)(LB + O_RED8);
  u16*   WnB  = (u16*)(LB + O_WNB);
  u16*   xA   = (u16*)(LB + O_XA);
  float* xloc = (float*)(LB + O_XLOC);
  float* anx  = (float*)(LB + O_ANX);
  float* degs = (float*)(LB + O_DEG);

  const int tid = threadIdx.x, lane = tid & 63, wave = tid >> 6;
  const int i0 = blockIdx.x * RPB;

  // ---- pack adj row (wave = row) -> adjL A-tiles + deg ----
  {
    int j0 = lane * 24;
    const float* src = p.adj + (size_t)(i0 + wave) * NN + j0;
    float ds = 0.f;
#pragma unroll
    for (int g = 0; g < 3; ++g) {
      bf16x8 v;
#pragma unroll
      for (int jj = 0; jj < 8; ++jj) {
        float f = src[g * 8 + jj];
        ds += f;
        v[jj] = (short)f2bf(f);
      }
      int k = j0 + g * 8;
      *(bf16x8*)&adjL[(k >> 5) * 512 + ((k & 31) >> 3) * 128 + wave * 8] = v;
    }
#pragma unroll
    for (int off = 32; off; off >>= 1) ds += __shfl_xor(ds, off, 64);
    if (lane == 0) degs[wave] = ds;
  }
  // ---- stage x row (wave = row) ----
  {
    const float4* src = (const float4*)(p.x + (size_t)(i0 + wave) * FF);
    float4* dst = (float4*)(xr + wave * FF);
    dst[lane] = src[lane];
    dst[lane + 64] = src[lane + 64];
  }
  __syncthreads();

  // ---- phase 0: t1 row (i0+wave) = x_row @ W1, VALU ----
  {
    const int g4 = lane >> 4, c4 = (lane & 15) * 4;
    float4 acc = {0.f, 0.f, 0.f, 0.f};
#pragma unroll 8
    for (int j = 0; j < FF; j += 4) {
      float4 t = *(const float4*)(p.W1 + (size_t)(j + g4) * HH + c4);
      float a = xr[wave * FF + j + g4];
      acc.x = fmaf(a, t.x, acc.x);
      acc.y = fmaf(a, t.y, acc.y);
      acc.z = fmaf(a, t.z, acc.z);
      acc.w = fmaf(a, t.w, acc.w);
    }
    acc.x += __shfl_xor(acc.x, 16, 64); acc.y += __shfl_xor(acc.y, 16, 64);
    acc.z += __shfl_xor(acc.z, 16, 64); acc.w += __shfl_xor(acc.w, 16, 64);
    acc.x += __shfl_xor(acc.x, 32, 64); acc.y += __shfl_xor(acc.y, 32, 64);
    acc.z += __shfl_xor(acc.z, 32, 64); acc.w += __shfl_xor(acc.w, 32, 64);
    if (lane < 16) {
      int k = i0 + wave;
      p.t1T[bidx(k, lane * 4 + 0)] = f2bf(acc.x);
      p.t1T[bidx(k, lane * 4 + 1)] = f2bf(acc.y);
      p.t1T[bidx(k, lane * 4 + 2)] = f2bf(acc.z);
      p.t1T[bidx(k, lane * 4 + 3)] = f2bf(acc.w);
    }
  }
  // ---- adj A-fragments for this wave's 3 k-steps -> registers (all layers) ----
  bf16x8 afr[3];
#pragma unroll
  for (int s = 0; s < 3; ++s)
    afr[s] = *(const bf16x8*)&adjL[(wave * 3 + s) * 512 + lane * 8];
  __syncthreads();  // everyone done with adjL/xr; region becomes TTl

  pack_wnb(WnB, p.W2, tid);
  gbar(p.bar, NB);

  // ---- layers ----
#pragma unroll 1
  for (int l = 0; l < 3; ++l) {
    const u16* TT    = l == 0 ? p.t1T : (l == 1 ? p.B2T : p.B3T);
    const float* bia = l == 0 ? p.b1 : (l == 1 ? p.b2 : p.b3);
    u16* Bout        = l == 0 ? p.B2T : p.B3T;

    f32x4 acc[4] = {{0, 0, 0, 0}, {0, 0, 0, 0}, {0, 0, 0, 0}, {0, 0, 0, 0}};
#pragma unroll
    for (int h = 0; h < 2; ++h) {
      // stage this wave's own 6KB of the column-half via global_load_lds
      {
        const char* gsrc = (const char*)TT + (size_t)h * 98304 + wave * 6144 +
                           (size_t)lane * 16;
        char* ldst = LB + O_TTL + wave * 6144;  // wave-uniform base
        asm volatile("s_waitcnt lgkmcnt(0)" ::: "memory");  // prior reads done
#pragma unroll
        for (int r = 0; r < 6; ++r)
          gl_lds16(gsrc + r * 1024, ldst + r * 1024);
      }
      asm volatile("s_waitcnt vmcnt(0)" ::: "memory");
      __builtin_amdgcn_sched_barrier(0);
      // consume: 3 k-steps x 2 col-groups (cg = h*2+chi)
#pragma unroll
      for (int s = 0; s < 3; ++s)
#pragma unroll
        for (int chi = 0; chi < 2; ++chi) {
          bf16x8 b = *(const bf16x8*)(LB + O_TTL + wave * 6144 +
                                      (s * 2 + chi) * 1024 + lane * 16);
          acc[h * 2 + chi] = __builtin_amdgcn_mfma_f32_16x16x32_bf16(
              afr[s], b, acc[h * 2 + chi], 0, 0, 0);
        }
    }

    // ---- 8-wave reduction tree ----
    if (wave < 8) {
#pragma unroll
      for (int cg = 0; cg < 4; ++cg)
#pragma unroll
        for (int q = 0; q < 4; ++q)
          red8[((wave * 4 + cg) * 16 + ((lane >> 4) * 4 + q)) * 17 +
               (lane & 15)] = acc[cg][q];
    }
    __syncthreads();
    if (wave >= 8) {
#pragma unroll
      for (int cg = 0; cg < 4; ++cg)
#pragma unroll
        for (int q = 0; q < 4; ++q)
          red8[(((wave - 8) * 4 + cg) * 16 + ((lane >> 4) * 4 + q)) * 17 +
               (lane & 15)] += acc[cg][q];
    }
    __syncthreads();

    // ---- combine 8 segments + bias + deg term + activation ----
    {
      float v = bia[lane];
#pragma unroll
      for (int s = 0; s < 8; ++s)
        v += red8[((s * 4 + (lane >> 4)) * 16 + wave) * 17 + (lane & 15)];
      if (l >= 1) v += anx[wave * 65 + lane] * degs[wave];
      if (l == 0) v = fmaxf(v, 0.f);
      if (l == 1) v = v > 0.f ? v : expm1f(v);
      xloc[wave * 65 + lane] = v;
      xA[(lane >> 5) * 512 + ((lane & 31) >> 3) * 128 + wave * 8 +
         (lane & 7)] = f2bf(v);
    }
    __syncthreads();

    if (l < 2) {
      // ---- epilogue: [anx | Bout] = x @ [Wn_top | Wn_bot] via MFMA ----
      if (wave < 8) {
        f32x4 a2 = {0.f, 0.f, 0.f, 0.f};
#pragma unroll
        for (int s = 0; s < 2; ++s) {
          bf16x8 a = *(const bf16x8*)&xA[s * 512 + lane * 8];
          bf16x8 b = *(const bf16x8*)&WnB[(s * 8 + wave) * 512 + lane * 8];
          a2 = __builtin_amdgcn_mfma_f32_16x16x32_bf16(a, b, a2, 0, 0, 0);
        }
        int row = (lane >> 4) * 4, colg = lane & 15;
        if (wave < 4) {
          int c = wave * 16 + colg;
#pragma unroll
          for (int q = 0; q < 4; ++q) anx[(row + q) * 65 + c] = a2[q];
        } else {
          int c = (wave - 4) * 16 + colg;
          int kk0 = i0 + row;
          u16x4 v;
#pragma unroll
          for (int q = 0; q < 4; ++q) v[q] = f2bf(a2[q]);
          *(u16x4*)&Bout[bidx(kk0, c)] = v;  // 4 consecutive k slots
        }
      }
      __syncthreads();
      if (l == 0) pack_wnb(WnB, p.W3, tid);
      gbar(p.bar, (unsigned)((2 + l) * NB));
    } else {
      // ---- log_softmax: wave = row ----
      float v = xloc[wave * 65 + lane];
      float m = v;
#pragma unroll
      for (int off = 32; off; off >>= 1) m = fmaxf(m, __shfl_xor(m, off, 64));
      float e = expf(v - m);
      float ssum = e;
#pragma unroll
      for (int off = 32; off; off >>= 1) ssum += __shfl_xor(ssum, off, 64);
      p.out[(size_t)(i0 + wave) * HH + lane] = v - m - logf(ssum);
    }
  }
}

extern "C" void kernel_launch(void* const* d_in, const int* in_sizes, int n_in,
                              void* d_out, int out_size, void* d_ws,
                              size_t ws_size, hipStream_t stream) {
  Params p;
  p.x   = (const float*)d_in[0];
  p.adj = (const float*)d_in[2];  // adj1; d_in[1]/d_in[3] are dead inputs
  p.W1  = (const float*)d_in[4];
  p.b1  = (const float*)d_in[5];
  p.W2  = (const float*)d_in[6];
  p.b2  = (const float*)d_in[7];
  p.W3  = (const float*)d_in[8];
  p.b3  = (const float*)d_in[9];
  p.out = (float*)d_out;

  char* ws = (char*)d_ws;
  p.t1T = (u16*)ws;                  // 196,608 B each (2 halves x 96KB)
  p.B2T = (u16*)(ws + 196608);
  p.B3T = (u16*)(ws + 393216);
  p.bar = (unsigned*)(ws + 589824);

  hipMemsetAsync((void*)p.bar, 0, 128, stream);
  gcn_all<<<NB, NT, 0, stream>>>(p);
}

// Round 10
// 30.278 us; speedup vs baseline: 2.1537x; 1.8058x over previous
//
#include <hip/hip_runtime.h>
#include <cmath>

constexpr int NN   = 1536;      // nodes
constexpr int FF   = 512;       // in features
constexpr int HH   = 64;        // hidden
constexpr int RPB  = 16;        // rows per block
constexpr int NB   = NN / RPB;  // 96 blocks
constexpr int NT   = 1024;      // 16 waves
constexpr int KST  = NN / 32;   // 48 k-steps
constexpr int KST1 = FF / 32;   // 16 k-steps for x@W1

using f32x4  = __attribute__((ext_vector_type(4))) float;
using bf16x8 = __attribute__((ext_vector_type(8))) short;
using u16x4  = __attribute__((ext_vector_type(4))) unsigned short;
typedef unsigned short u16;

__device__ __forceinline__ u16 f2bf(float f) {  // RNE fp32 -> bf16
  unsigned u = __builtin_bit_cast(unsigned, f);
  return (u16)((u + 0x7fffu + ((u >> 16) & 1u)) >> 16);
}

// B-tile index for a [1536 k x 64 c] matrix, column-half contiguous:
// half (c>>5) spans a contiguous 96KB; within it, tile = kstep*2 + ((c>>4)&1).
__device__ __forceinline__ size_t bidx(int k, int c) {
  return (size_t)((c >> 5) * (KST * 2) + (k >> 5) * 2 + ((c >> 4) & 1)) * 512 +
         ((k & 31) >> 3) * 128 + (c & 15) * 8 + (k & 7);
}

__device__ __forceinline__ void gl_lds16(const void* g, void* l) {
  __builtin_amdgcn_global_load_lds(
      (const __attribute__((address_space(1))) unsigned*)g,
      (__attribute__((address_space(3))) unsigned*)l, 16, 0, 0);
}

__device__ __forceinline__ void pack_wnb(u16* WnB, const float* Wsrc, int tid) {
  // Bmat[k][j'], k 0..63, j' 0..127; j'<64 -> Wn[k][j'], else Wn[64+k][j'-64]
  int jp = tid & 127, kb = (tid >> 7) * 8;
  int srow0 = (jp >> 6) * 64, col = jp & 63;
#pragma unroll
  for (int i = 0; i < 8; ++i) {
    int k = kb + i;
    WnB[((k >> 5) * 8 + (jp >> 4)) * 512 + ((k & 31) >> 3) * 128 +
        (jp & 15) * 8 + (k & 7)] = f2bf(Wsrc[(size_t)(srow0 + k) * HH + col]);
  }
}

// ---- k_pre: adj -> adjT A-tiles + deg; t1 = x@W1 (MFMA) -> t1T B-tiles ----
__global__ __launch_bounds__(NT, 4) void k_pre(
    const float* __restrict__ x, const float* __restrict__ adj,
    const float* __restrict__ W1,
    u16* __restrict__ adjT, u16* __restrict__ t1T, float* __restrict__ deg) {
  __shared__ u16 Al[KST1 * 512];        // 16 KB
  __shared__ u16 Bl[KST1 * 4 * 512];    // 64 KB
  __shared__ u16 Jl[KST * 512];         // 48 KB
  __shared__ float red0[4][4][16][16];  // 16 KB
  const int tid = threadIdx.x, lane = tid & 63, wave = tid >> 6;
  const int i0 = blockIdx.x * RPB;

  {  // pack x rows -> Al (wave = row, lane: 8 k)
    int j0 = lane * 8;
    const float* src = x + (size_t)(i0 + wave) * FF + j0;
    bf16x8 v;
#pragma unroll
    for (int jj = 0; jj < 8; ++jj) v[jj] = (short)f2bf(src[jj]);
    *(bf16x8*)&Al[(j0 >> 5) * 512 + ((j0 & 31) >> 3) * 128 + wave * 8] = v;
  }
  {  // pack W1 -> Bl (thread: one k-row, 32 cols)
    int k = tid >> 1, c0 = (tid & 1) * 32;
    const float* src = W1 + (size_t)k * HH + c0;
    int base = (k >> 5) * 2048 + ((k & 31) >> 3) * 128 + (k & 7);
#pragma unroll 8
    for (int cc = 0; cc < 32; ++cc) {
      int c = c0 + cc;
      Bl[base + (c >> 4) * 512 + (c & 15) * 8] = f2bf(src[cc]);
    }
  }
  {  // pack adj slab -> Jl + deg (wave = row, lane: 24 k)
    int j0 = lane * 24;
    const float* src = adj + (size_t)(i0 + wave) * NN + j0;
    float ds = 0.f;
#pragma unroll
    for (int g = 0; g < 3; ++g) {
      bf16x8 v;
#pragma unroll
      for (int jj = 0; jj < 8; ++jj) {
        float f = src[g * 8 + jj];
        ds += f;
        v[jj] = (short)f2bf(f);
      }
      int k = j0 + g * 8;
      *(bf16x8*)&Jl[(k >> 5) * 512 + ((k & 31) >> 3) * 128 + wave * 8] = v;
    }
#pragma unroll
    for (int off = 32; off; off >>= 1) ds += __shfl_xor(ds, off, 64);
    if (lane == 0) deg[i0 + wave] = ds;
  }
  __syncthreads();

  {  // Jl -> adjT (48 KB linear)
    const float4* srcv = (const float4*)Jl;
    float4* dstv = (float4*)(adjT + (size_t)blockIdx.x * KST * 512);
#pragma unroll
    for (int s = 0; s < 3; ++s) dstv[tid + s * NT] = srcv[tid + s * NT];
  }
  {  // MFMA: t1 = x @ W1. wave = (ks 0..3, cg 0..3)
    int ks = wave >> 2, cg = wave & 3;
    f32x4 acc = {0.f, 0.f, 0.f, 0.f};
#pragma unroll
    for (int s = 0; s < 4; ++s) {
      int t = ks * 4 + s;
      bf16x8 a = *(const bf16x8*)&Al[t * 512 + lane * 8];
      bf16x8 b = *(const bf16x8*)&Bl[(t * 4 + cg) * 512 + lane * 8];
      acc = __builtin_amdgcn_mfma_f32_16x16x32_bf16(a, b, acc, 0, 0, 0);
    }
#pragma unroll
    for (int q = 0; q < 4; ++q)
      red0[ks][cg][(lane >> 4) * 4 + q][lane & 15] = acc[q];
  }
  __syncthreads();
  {  // combine 4 k-segments, write t1T (column-half B-tiles)
    int r = wave, c = lane;
    float v = red0[0][c >> 4][r][c & 15] + red0[1][c >> 4][r][c & 15] +
              red0[2][c >> 4][r][c & 15] + red0[3][c >> 4][r][c & 15];
    t1T[bidx(i0 + r, c)] = f2bf(v);
  }
}

// ---- k_layer: y = adj@T via MFMA, T staged per-wave with global_load_lds ----
// MODE 0: x = relu(y+b);          outA = x@Wn_top (f32), outBT = x@Wn_bot (tiles)
// MODE 1: x = elu(Ain*deg+y+b);   outA/outBT as above
// MODE 2: x = Ain*deg+y+b;        out = log_softmax(x)
template <int MODE>
__global__ __launch_bounds__(NT, 4) void k_layer(
    const u16* __restrict__ adjT, const u16* __restrict__ TT,
    const float* __restrict__ Ain, const float* __restrict__ deg,
    const float* __restrict__ bias, const float* __restrict__ Wn,
    float* __restrict__ outA, u16* __restrict__ outBT,
    float* __restrict__ out) {
  // LDS union (bytes): TTL [16 waves][6144] @0 (98304), red8 @98304 (34816),
  // WnB @133120 (16384), xA @149504 (2048), xloc @151552 (4160) -> 155712 B
  __shared__ __attribute__((aligned(16))) char LB[155712];
  float* red8 = (float*)(LB + 98304);  // [8][4][16][17]
  u16*   WnB  = (u16*)(LB + 133120);   // 16 tiles x 512 u16
  u16*   xA   = (u16*)(LB + 149504);   // x as A-tiles [2][512]
  float* xloc = (float*)(LB + 151552); // [16][65]

  const int tid = threadIdx.x, lane = tid & 63, wave = tid >> 6;
  const int i0 = blockIdx.x * RPB;

  // adj A-fragments: 3 coalesced b128 loads (independent, in flight together)
  const u16* ja = adjT + (size_t)blockIdx.x * (KST * 512);
  bf16x8 afr[3];
#pragma unroll
  for (int s = 0; s < 3; ++s)
    afr[s] = *(const bf16x8*)(ja + (wave * 3 + s) * 512 + lane * 8);

  if (MODE < 2) pack_wnb(WnB, Wn, tid);
  float dg = 0.f;
  if (MODE >= 1) dg = deg[i0 + wave];

  f32x4 acc[4] = {{0, 0, 0, 0}, {0, 0, 0, 0}, {0, 0, 0, 0}, {0, 0, 0, 0}};
#pragma unroll
  for (int h = 0; h < 2; ++h) {
    {  // stage this wave's 6KB of column-half h (wave-private LDS region)
      const char* gsrc = (const char*)TT + (size_t)h * 98304 + wave * 6144 +
                         (size_t)lane * 16;
      char* ldst = LB + wave * 6144;
      asm volatile("s_waitcnt lgkmcnt(0)" ::: "memory");  // prior LDS reads done
#pragma unroll
      for (int r = 0; r < 6; ++r) gl_lds16(gsrc + r * 1024, ldst + r * 1024);
    }
    asm volatile("s_waitcnt vmcnt(0)" ::: "memory");
    __builtin_amdgcn_sched_barrier(0);
#pragma unroll
    for (int s = 0; s < 3; ++s)
#pragma unroll
      for (int chi = 0; chi < 2; ++chi) {
        bf16x8 b = *(const bf16x8*)(LB + wave * 6144 + (s * 2 + chi) * 1024 +
                                    lane * 16);
        acc[h * 2 + chi] = __builtin_amdgcn_mfma_f32_16x16x32_bf16(
            afr[s], b, acc[h * 2 + chi], 0, 0, 0);
      }
  }

  // 8-wave reduction tree (padded stride 17 -> <=2-way banks)
  if (wave < 8) {
#pragma unroll
    for (int cg = 0; cg < 4; ++cg)
#pragma unroll
      for (int q = 0; q < 4; ++q)
        red8[((wave * 4 + cg) * 16 + ((lane >> 4) * 4 + q)) * 17 +
             (lane & 15)] = acc[cg][q];
  }
  __syncthreads();
  if (wave >= 8) {
#pragma unroll
    for (int cg = 0; cg < 4; ++cg)
#pragma unroll
      for (int q = 0; q < 4; ++q)
        red8[(((wave - 8) * 4 + cg) * 16 + ((lane >> 4) * 4 + q)) * 17 +
             (lane & 15)] += acc[cg][q];
  }
  __syncthreads();

  {  // combine 8 segments + bias + deg term + activation
    float v = bias[lane];
#pragma unroll
    for (int s = 0; s < 8; ++s)
      v += red8[((s * 4 + (lane >> 4)) * 16 + wave) * 17 + (lane & 15)];
    if (MODE >= 1) v += Ain[(size_t)(i0 + wave) * HH + lane] * dg;
    if (MODE == 0) v = fmaxf(v, 0.f);
    if (MODE == 1) v = v > 0.f ? v : expm1f(v);
    xloc[wave * 65 + lane] = v;
    if (MODE < 2)
      xA[(lane >> 5) * 512 + ((lane & 31) >> 3) * 128 + wave * 8 +
         (lane & 7)] = f2bf(v);
  }
  __syncthreads();

  if (MODE < 2) {
    // epilogue: [outA | outBT] = x @ [Wn_top | Wn_bot] via MFMA (8 waves)
    if (wave < 8) {
      f32x4 a2 = {0.f, 0.f, 0.f, 0.f};
#pragma unroll
      for (int s = 0; s < 2; ++s) {
        bf16x8 a = *(const bf16x8*)&xA[s * 512 + lane * 8];
        bf16x8 b = *(const bf16x8*)&WnB[(s * 8 + wave) * 512 + lane * 8];
        a2 = __builtin_amdgcn_mfma_f32_16x16x32_bf16(a, b, a2, 0, 0, 0);
      }
      int row = (lane >> 4) * 4, colg = lane & 15;
      if (wave < 4) {
        int c = wave * 16 + colg;
#pragma unroll
        for (int q = 0; q < 4; ++q)
          outA[(size_t)(i0 + row + q) * HH + c] = a2[q];
      } else {
        int c = (wave - 4) * 16 + colg;
        u16x4 v;
#pragma unroll
        for (int q = 0; q < 4; ++q) v[q] = f2bf(a2[q]);
        *(u16x4*)&outBT[bidx(i0 + row, c)] = v;  // 4 consecutive k slots
      }
    }
  } else {
    // log_softmax: wave = row
    float v = xloc[wave * 65 + lane];
    float m = v;
#pragma unroll
    for (int off = 32; off; off >>= 1) m = fmaxf(m, __shfl_xor(m, off, 64));
    float e = expf(v - m);
    float ssum = e;
#pragma unroll
    for (int off = 32; off; off >>= 1) ssum += __shfl_xor(ssum, off, 64);
    out[(size_t)(i0 + wave) * HH + lane] = v - m - logf(ssum);
  }
}

extern "C" void kernel_launch(void* const* d_in, const int* in_sizes, int n_in,
                              void* d_out, int out_size, void* d_ws,
                              size_t ws_size, hipStream_t stream) {
  const float* x   = (const float*)d_in[0];
  const float* adj = (const float*)d_in[2];  // adj1; d_in[1]/[3] are dead
  const float* W1  = (const float*)d_in[4];
  const float* b1  = (const float*)d_in[5];
  const float* W2  = (const float*)d_in[6];
  const float* b2  = (const float*)d_in[7];
  const float* W3  = (const float*)d_in[8];
  const float* b3  = (const float*)d_in[9];
  float* out = (float*)d_out;

  char* ws = (char*)d_ws;
  u16* adjT = (u16*)ws;                   // 4,718,592 B
  u16* t1T  = (u16*)(ws + 4718592);       // 196,608 B each (2 x 96KB halves)
  u16* B2T  = (u16*)(ws + 4915200);
  u16* B3T  = (u16*)(ws + 5111808);
  float* A2 = (float*)(ws + 5308416);     // 393,216 B each
  float* A3 = (float*)(ws + 5701632);
  float* dg = (float*)(ws + 6094848);     // 6,144 B

  k_pre<<<NB, NT, 0, stream>>>(x, adj, W1, adjT, t1T, dg);
  k_layer<0><<<NB, NT, 0, stream>>>(adjT, t1T, nullptr, nullptr, b1, W2, A2,
                                    B2T, nullptr);
  k_layer<1><<<NB, NT, 0, stream>>>(adjT, B2T, A2, dg, b2, W3, A3, B3T,
                                    nullptr);
  k_layer<2><<<NB, NT, 0, stream>>>(adjT, B3T, A3, dg, b3, nullptr, nullptr,
                                    nullptr, out);
}